// Round 6
// baseline (1208.874 us; speedup 1.0000x reference)
//
#include <hip/hip_runtime.h>
#include <hip/hip_bf16.h>
#include <math.h>

using bf16 = __hip_bfloat16;

#define H_IMG 128
#define W_IMG 128
#define C_IN  200
#define NCLS  16
#define N0    16384
#define N1    4096
#define N2    1024
#define KNB   16
#define EPS   1e-5f
#define SLOPE 0.01f

__device__ __forceinline__ float leaky(float v) { return v >= 0.f ? v : SLOPE * v; }
__device__ __forceinline__ float ldw(const void* p, long i, int fl) {
    return fl ? ((const float*)p)[i] : __bfloat162float(((const bf16*)p)[i]);
}
__device__ __forceinline__ float4 ld4(const float* p, long i) {
    return *reinterpret_cast<const float4*>(p + i);
}
__device__ __forceinline__ float4 ld4(const bf16* p, long i) {
    const ushort4 u = *reinterpret_cast<const ushort4*>(reinterpret_cast<const unsigned short*>(p) + i);
    float4 r;
    r.x = __uint_as_float((unsigned)u.x << 16);
    r.y = __uint_as_float((unsigned)u.y << 16);
    r.z = __uint_as_float((unsigned)u.z << 16);
    r.w = __uint_as_float((unsigned)u.w << 16);
    return r;
}

// ---------- per-block dtype detect ----------
__device__ __forceinline__ int block_detect(const unsigned short* __restrict__ x) {
    __shared__ int cnt_s;
    if (threadIdx.x == 0) cnt_s = 0;
    __syncthreads();
    int cnt = 0;
    for (int i = threadIdx.x; i < 4096; i += blockDim.x) {
        unsigned short e = (unsigned short)((x[i] >> 7) & 0xFF);
        if (e >= 0xC0) cnt++;
    }
#pragma unroll
    for (int off = 32; off > 0; off >>= 1) cnt += __shfl_xor(cnt, off, 64);
    if ((threadIdx.x & 63) == 0) atomicAdd(&cnt_s, cnt);
    __syncthreads();
    return cnt_s > 32 ? 1 : 0;
}

// ---------- generic one-block BN-reduce + weight fold ----------
// partials: channel t < splitC from pA (npA slots), else pB (npB slots).
// W1: c-major [CI][Co1], raw dtype unless w1f32. Writes WF1 (f32, c-major) + BF1.
// Optional W2 likewise.
__device__ void fold_layer(const float2* __restrict__ pA, int npA, int splitC,
                           const float2* __restrict__ pB, int npB,
                           int CI, float Pinv, const void* g, const void* bt, int fl,
                           const void* W1, const void* b1, int Co1, int w1f32,
                           const void* W2, const void* b2, int Co2,
                           float* __restrict__ WF1, float* __restrict__ BF1,
                           float* __restrict__ WF2, float* __restrict__ BF2,
                           float* al, float* be) {
    int t = threadIdx.x;
    if (t < CI) {
        const float2* src = (t < splitC) ? pA + (long)t * npA : pB + (long)(t - splitC) * npB;
        int np = (t < splitC) ? npA : npB;
        float s = 0.f, s2 = 0.f;
        const float4* p4 = (const float4*)src;
        for (int i = 0; i < (np >> 1); i++) { float4 v = p4[i]; s += v.x + v.z; s2 += v.y + v.w; }
        float mu = s * Pinv;
        float var = s2 * Pinv - mu * mu;
        float aa = rsqrtf(var + EPS) * ldw(g, t, fl);
        al[t] = aa;
        be[t] = ldw(bt, t, fl) - mu * aa;
    }
    __syncthreads();
    for (int e = t; e < CI * Co1; e += 256) {
        int c = e / Co1;
        float w = w1f32 ? ((const float*)W1)[e] : ldw(W1, e, fl);
        WF1[e] = w * al[c];
    }
    if (t < Co1) {
        float s = ldw(b1, t, fl);
        for (int c = 0; c < CI; c++) {
            float w = w1f32 ? ((const float*)W1)[(long)c * Co1 + t] : ldw(W1, (long)c * Co1 + t, fl);
            s += w * be[c];
        }
        BF1[t] = s;
    }
    if (W2) {
        for (int e = t; e < CI * Co2; e += 256) {
            int c = e / Co2;
            WF2[e] = ldw(W2, e, fl) * al[c];
        }
        if (t < Co2) {
            float s = ldw(b2, t, fl);
            for (int c = 0; c < CI; c++) s += ldw(W2, (long)c * Co2 + t, fl) * be[c];
            BF2[t] = s;
        }
    }
}

// last-block detection: returns true in exactly one block, after all blocks' prior
// global writes are device-visible.
__device__ __forceinline__ bool last_block(int* cnt, int nblk, int* lds_flag) {
    __syncthreads();                       // all waves drained their stores (vmcnt0 before barrier)
    if (threadIdx.x == 0) {
        __threadfence();                   // device-scope release (L2 writeback)
        *lds_flag = (atomicAdd(cnt, 1) == nblk - 1);
    }
    __syncthreads();
    if (!*lds_flag) return false;
    __threadfence();                       // acquire side
    return true;
}

// ---------------- K0: prep — detect + zero counters + transpose o-major 1x1 weights ----------------
__global__ __launch_bounds__(256) void prep_kernel(const void* __restrict__ x,
                                                   const void* __restrict__ hpw, const void* __restrict__ tpw,
                                                   float* __restrict__ WHc, float* __restrict__ WTc,
                                                   int* __restrict__ dflag, int* __restrict__ cnts) {
    int fl = block_detect((const unsigned short*)x);
    if (blockIdx.x == 0 && threadIdx.x == 0) *dflag = fl;
    if (blockIdx.x == 0 && threadIdx.x < 8) cnts[threadIdx.x] = 0;
    if (blockIdx.x < 8) {
        for (long e = blockIdx.x * 256 + threadIdx.x; e < 128L * C_IN; e += 8 * 256) {
            int j = (int)(e / C_IN), c = (int)(e - (long)j * C_IN);
            WHc[(long)c * 128 + j] = ldw(hpw, e, fl);
        }
    } else {
        for (long e = (blockIdx.x - 8) * 256 + threadIdx.x; e < 128L * 192; e += 8 * 256) {
            int j = (int)(e / 192), c = (int)(e - (long)j * 192);
            WTc[(long)c * 128 + j] = ldw(tpw, e, fl);
        }
    }
}

// ---------------- K1: head BN stage A + last-block fold of head 1x1 ----------------
__global__ __launch_bounds__(256) void bnx_kernel(const void* __restrict__ X, float2* __restrict__ part,
                                                  const float* __restrict__ WHc, const void* hpb,
                                                  const void* hg, const void* hb_,
                                                  float* __restrict__ WFh, float* __restrict__ BFh,
                                                  int* cnt) {
    int fl = block_detect((const unsigned short*)X);
    int b = blockIdx.x, t = threadIdx.x;
    if (t < C_IN) {
        float s = 0.f, s2 = 0.f;
        if (fl) {
            const float* p = (const float*)X + (long)b * 64 * C_IN + t;
            for (int r = 0; r < 64; r++) { float v = p[(long)r * C_IN]; s += v; s2 += v * v; }
        } else {
            const bf16* p = (const bf16*)X + (long)b * 64 * C_IN + t;
            for (int r = 0; r < 64; r++) { float v = __bfloat162float(p[(long)r * C_IN]); s += v; s2 += v * v; }
        }
        part[(long)t * 256 + b] = make_float2(s, s2);
    }
    __shared__ int lastf;
    if (!last_block(cnt, 256, &lastf)) return;
    __shared__ float al[256], be[256];
    fold_layer(part, 256, C_IN, part, 256, C_IN, 1.f / (float)N0, hg, hb_, fl,
               WHc, hpb, 128, 1, nullptr, nullptr, 0, WFh, BFh, nullptr, nullptr, al, be);
}

// ---------------- LDS-tiled GEMM bodies (R4-proven) ----------------
template <typename T, int CI, int KT, int CAT>
__device__ __forceinline__ void gemmT_body(const T* __restrict__ In, const float* __restrict__ A2,
                                           const float* __restrict__ Wf, const float* __restrict__ Bf,
                                           float* __restrict__ Out) {
    __shared__ float wls[KT * 128];
    int t = threadIdx.x;
    int jq = t & 31, rp = t >> 5;
    int n0 = blockIdx.x * 16;
    int r0 = n0 + rp * 2, r1 = r0 + 1;
    float4 a0 = *reinterpret_cast<const float4*>(Bf + jq * 4);
    float4 a1 = a0;
    for (int kt = 0; kt < CI; kt += KT) {
        for (int e = t * 4; e < KT * 128; e += 1024)
            *reinterpret_cast<float4*>(&wls[e]) = *reinterpret_cast<const float4*>(&Wf[(long)kt * 128 + e]);
        __syncthreads();
        for (int cc = 0; cc < KT; cc += 4) {
            int c = kt + cc;
            float4 x0, x1;
            if (CAT) {
                if (c < 64) {
                    x0 = ld4(A2 + (long)(r0 >> 2) * 64, c);
                    x1 = ld4(A2 + (long)(r1 >> 2) * 64, c);
                } else {
                    x0 = ld4((const float*)(const void*)In + (long)r0 * 128, c - 64);
                    x1 = ld4((const float*)(const void*)In + (long)r1 * 128, c - 64);
                }
            } else {
                x0 = ld4(In + (long)r0 * CI, c);
                x1 = ld4(In + (long)r1 * CI, c);
            }
            const float* wp = &wls[cc * 128 + jq * 4];
            float4 w0 = *reinterpret_cast<const float4*>(wp);
            float4 w1 = *reinterpret_cast<const float4*>(wp + 128);
            float4 w2 = *reinterpret_cast<const float4*>(wp + 256);
            float4 w3 = *reinterpret_cast<const float4*>(wp + 384);
            a0.x += x0.x * w0.x; a0.y += x0.x * w0.y; a0.z += x0.x * w0.z; a0.w += x0.x * w0.w;
            a1.x += x1.x * w0.x; a1.y += x1.x * w0.y; a1.z += x1.x * w0.z; a1.w += x1.x * w0.w;
            a0.x += x0.y * w1.x; a0.y += x0.y * w1.y; a0.z += x0.y * w1.z; a0.w += x0.y * w1.w;
            a1.x += x1.y * w1.x; a1.y += x1.y * w1.y; a1.z += x1.y * w1.z; a1.w += x1.y * w1.w;
            a0.x += x0.z * w2.x; a0.y += x0.z * w2.y; a0.z += x0.z * w2.z; a0.w += x0.z * w2.w;
            a1.x += x1.z * w2.x; a1.y += x1.z * w2.y; a1.z += x1.z * w2.z; a1.w += x1.z * w2.w;
            a0.x += x0.w * w3.x; a0.y += x0.w * w3.y; a0.z += x0.w * w3.z; a0.w += x0.w * w3.w;
            a1.x += x1.w * w3.x; a1.y += x1.w * w3.y; a1.z += x1.w * w3.z; a1.w += x1.w * w3.w;
        }
        __syncthreads();
    }
    a0.x = leaky(a0.x); a0.y = leaky(a0.y); a0.z = leaky(a0.z); a0.w = leaky(a0.w);
    a1.x = leaky(a1.x); a1.y = leaky(a1.y); a1.z = leaky(a1.z); a1.w = leaky(a1.w);
    *reinterpret_cast<float4*>(Out + (long)r0 * 128 + jq * 4) = a0;
    *reinterpret_cast<float4*>(Out + (long)r1 * 128 + jq * 4) = a1;
}

__global__ __launch_bounds__(256) void gemmT_head_kernel(const void* In, const float* Wf, const float* Bf,
                                                         float* Out, const int* dflag) {
    if (*dflag) gemmT_body<float, C_IN, 40, 0>((const float*)In, nullptr, Wf, Bf, Out);
    else        gemmT_body<bf16,  C_IN, 40, 0>((const bf16*)In, nullptr, Wf, Bf, Out);
}

__global__ __launch_bounds__(256) void gemmT_tail_kernel(const float* InB, const float* InA,
                                                         const float* Wf, const float* Bf, float* Out) {
    gemmT_body<float, 192, 48, 1>(InB, InA, Wf, Bf, Out);
}

// ---------------- small register GEMMs (N1/N2 scale, R4-proven) ----------------
template <typename T, int ACT>
__device__ __forceinline__ void gemm4_body(const T* __restrict__ In, const float* __restrict__ Wf,
                                           const float* __restrict__ Bf, float* __restrict__ Out,
                                           int Ci, int Co, int blk) {
    int tid = blk * 256 + threadIdx.x;
    int Coq = Co >> 2;
    int n = tid / Coq;
    int j4 = (tid - n * Coq) << 2;
    const T* in = In + (long)n * Ci;
    const float* wp = Wf + j4;
    float4 acc = *reinterpret_cast<const float4*>(Bf + j4);
    for (int c = 0; c < Ci; c += 4) {
        float4 xv = ld4(in, c);
        float4 w0 = *reinterpret_cast<const float4*>(wp + (long)c * Co);
        float4 w1 = *reinterpret_cast<const float4*>(wp + (long)(c + 1) * Co);
        float4 w2 = *reinterpret_cast<const float4*>(wp + (long)(c + 2) * Co);
        float4 w3 = *reinterpret_cast<const float4*>(wp + (long)(c + 3) * Co);
        acc.x += xv.x * w0.x; acc.y += xv.x * w0.y; acc.z += xv.x * w0.z; acc.w += xv.x * w0.w;
        acc.x += xv.y * w1.x; acc.y += xv.y * w1.y; acc.z += xv.y * w1.z; acc.w += xv.y * w1.w;
        acc.x += xv.z * w2.x; acc.y += xv.z * w2.y; acc.z += xv.z * w2.z; acc.w += xv.z * w2.w;
        acc.x += xv.w * w3.x; acc.y += xv.w * w3.y; acc.z += xv.w * w3.z; acc.w += xv.w * w3.w;
    }
    if (ACT) { acc.x = leaky(acc.x); acc.y = leaky(acc.y); acc.z = leaky(acc.z); acc.w = leaky(acc.w); }
    *reinterpret_cast<float4*>(Out + (long)n * Co + j4) = acc;
}

template <int ACT, int SPLIT>
__device__ __forceinline__ void gemm4cat_body(const float* __restrict__ InA, int sA,
                                              const float* __restrict__ InB, int sB,
                                              const float* __restrict__ Wf, const float* __restrict__ Bf,
                                              float* __restrict__ Out, int Ci, int Co, int blk) {
    int tid = blk * 256 + threadIdx.x;
    int Coq = Co >> 2;
    int n = tid / Coq;
    int j4 = (tid - n * Coq) << 2;
    const float* ia = InA + (long)(n >> 2) * sA;
    const float* ib = InB + (long)n * sB;
    const float* wp = Wf + j4;
    float4 acc = *reinterpret_cast<const float4*>(Bf + j4);
    for (int c = 0; c < Ci; c += 4) {
        float4 xv = (c < SPLIT) ? *reinterpret_cast<const float4*>(ia + c)
                                : *reinterpret_cast<const float4*>(ib + (c - SPLIT));
        float4 w0 = *reinterpret_cast<const float4*>(wp + (long)c * Co);
        float4 w1 = *reinterpret_cast<const float4*>(wp + (long)(c + 1) * Co);
        float4 w2 = *reinterpret_cast<const float4*>(wp + (long)(c + 2) * Co);
        float4 w3 = *reinterpret_cast<const float4*>(wp + (long)(c + 3) * Co);
        acc.x += xv.x * w0.x; acc.y += xv.x * w0.y; acc.z += xv.x * w0.z; acc.w += xv.x * w0.w;
        acc.x += xv.y * w1.x; acc.y += xv.y * w1.y; acc.z += xv.y * w1.z; acc.w += xv.y * w1.w;
        acc.x += xv.z * w2.x; acc.y += xv.z * w2.y; acc.z += xv.z * w2.z; acc.w += xv.z * w2.w;
        acc.x += xv.w * w3.x; acc.y += xv.w * w3.y; acc.z += xv.w * w3.z; acc.w += xv.w * w3.w;
    }
    if (ACT) { acc.x = leaky(acc.x); acc.y = leaky(acc.y); acc.z = leaky(acc.z); acc.w = leaky(acc.w); }
    *reinterpret_cast<float4*>(Out + (long)n * Co + j4) = acc;
}

__global__ __launch_bounds__(256) void gemm2_f32_kernel(const float* In,
                                                        const float* W1, const float* B1, float* O1, int Co1,
                                                        const float* W2, const float* B2, float* O2, int Co2,
                                                        int Ci, int nb1) {
    int b = blockIdx.x;
    if (b < nb1) gemm4_body<float, 0>(In, W1, B1, O1, Ci, Co1, b);
    else         gemm4_body<float, 0>(In, W2, B2, O2, Ci, Co2, b - nb1);
}

template <int SPLIT>
__global__ __launch_bounds__(256) void gemm2cat_kernel(const float* InA, int sA, const float* InB, int sB,
                                                       const float* W1, const float* B1, float* O1, int Co1,
                                                       const float* W2, const float* B2, float* O2, int Co2,
                                                       int Ci, int nb1) {
    int b = blockIdx.x;
    if (b < nb1) gemm4cat_body<0, SPLIT>(InA, sA, InB, sB, W1, B1, O1, Ci, Co1, b);
    else         gemm4cat_body<0, SPLIT>(InA, sA, InB, sB, W2, B2, O2, Ci, Co2, b - nb1);
}

// ---------------- depthwise 5x5 helpers ----------------
__device__ __forceinline__ void dw_load(const void* dwp, const void* dbp, float* wl, float* bl, int fl) {
    int t = threadIdx.x;
    for (int e = t; e < 25 * 128; e += 256) {
        int o = e / 25, i = e - o * 25;
        wl[i * 128 + o] = ldw(dwp, e, fl);
    }
    if (t < 128) bl[t] = ldw(dbp, t, fl);
}

__device__ __forceinline__ float4 dw_compute(int p, int o0, const float* __restrict__ In,
                                             const float* wl, const float* bl) {
    int h = p >> 7, w = p & 127;
    float4 acc = *reinterpret_cast<const float4*>(&bl[o0]);
#pragma unroll
    for (int dh = -2; dh <= 2; dh++) {
        int hh = h + dh;
        if ((unsigned)hh >= (unsigned)H_IMG) continue;
#pragma unroll
        for (int dv = -2; dv <= 2; dv++) {
            int ww = w + dv;
            if ((unsigned)ww >= (unsigned)W_IMG) continue;
            float4 iv = *reinterpret_cast<const float4*>(&In[(long)(((hh << 7) + ww) << 7) + o0]);
            float4 wv = *reinterpret_cast<const float4*>(&wl[((dh + 2) * 5 + (dv + 2)) * 128 + o0]);
            acc.x += iv.x * wv.x; acc.y += iv.y * wv.y; acc.z += iv.z * wv.z; acc.w += iv.w * wv.w;
        }
    }
    acc.x = leaky(acc.x); acc.y = leaky(acc.y); acc.z = leaky(acc.z); acc.w = leaky(acc.w);
    return acc;
}

// ---------------- K3: head dw + pool4 + stats + last-block e0 fold (grid 512) ----------------
__global__ __launch_bounds__(256) void dwpool_kernel(const float* __restrict__ In, const void* dwp, const void* dbp,
                                                     float* __restrict__ R1out, float* __restrict__ H1b,
                                                     float2* __restrict__ pE0, float2* __restrict__ pTb,
                                                     const int* dflag,
                                                     const void* e0_wt, const void* e0_bt,
                                                     const void* e0_wo, const void* e0_bo,
                                                     const void* e0_g, const void* e0_b,
                                                     float* WF1, float* BF1, float* WF2, float* BF2,
                                                     int* cnt) {
    __shared__ float wl[25 * 128];
    __shared__ float bl[128];
    __shared__ float sm[8 * 132];
    int fl = *dflag;
    dw_load(dwp, dbp, wl, bl, fl);
    __syncthreads();
    int t = threadIdx.x;
    int o0 = (t & 31) << 2, pxl = t >> 5;
    float s = 0.f, s2 = 0.f, rs = 0.f, rs2 = 0.f;
    for (int it = 0; it < 4; it++) {
        int p = blockIdx.x * 32 + it * 8 + pxl;
        float4 acc = dw_compute(p, o0, In, wl, bl);
        *reinterpret_cast<float4*>(&R1out[(long)p * 128 + o0]) = acc;
        *reinterpret_cast<float4*>(&sm[pxl * 132 + o0]) = acc;
        __syncthreads();
        if (t < 128) {
#pragma unroll
            for (int g = 0; g < 2; g++) {
                float v0 = sm[(g * 4 + 0) * 132 + t], v1 = sm[(g * 4 + 1) * 132 + t];
                float v2 = sm[(g * 4 + 2) * 132 + t], v3 = sm[(g * 4 + 3) * 132 + t];
                float h = 0.25f * (v0 + v1 + v2 + v3);
                H1b[(long)(blockIdx.x * 8 + it * 2 + g) * 128 + t] = h;
                s += h; s2 += h * h;
                rs += v0 + v1 + v2 + v3;
                rs2 += v0 * v0 + v1 * v1 + v2 * v2 + v3 * v3;
            }
        }
        __syncthreads();
    }
    if (t < 128) {
        pE0[(long)t * 512 + blockIdx.x] = make_float2(s, s2);
        pTb[(long)t * 512 + blockIdx.x] = make_float2(rs, rs2);
    }
    __shared__ int lastf;
    if (!last_block(cnt, 512, &lastf)) return;
    __shared__ float al[256], be[256];
    fold_layer(pE0, 512, 128, pE0, 512, 128, 1.f / (float)N1, e0_g, e0_b, fl,
               e0_wt, e0_bt, 128, 0, e0_wo, e0_bo, 64, WF1, BF1, WF2, BF2, al, be);
}

// ---------------- K11: tail dw + classifier + softmax (grid 2048) ----------------
__global__ __launch_bounds__(256) void dwcls_kernel(const float* __restrict__ In, const void* dwp, const void* dbp,
                                                    const void* wsw, const void* wb, void* __restrict__ out,
                                                    const int* dflag) {
    __shared__ float wl[25 * 128];
    __shared__ float bl[128];
    __shared__ float cw[2048];
    __shared__ float F[8 * 132];
    int fl = *dflag;
    dw_load(dwp, dbp, wl, bl, fl);
    int t = threadIdx.x;
    for (int e = t; e < 2048; e += 256) cw[e] = ldw(wsw, e, fl);
    __syncthreads();
    int o0 = (t & 31) << 2, pxl = t >> 5;
    int p = blockIdx.x * 8 + pxl;
    float4 acc = dw_compute(p, o0, In, wl, bl);
    *reinterpret_cast<float4*>(&F[pxl * 132 + o0]) = acc;
    __syncthreads();
    if (t < 128) {
        int px = t >> 4, j = t & 15;
        float a = ldw(wb, j, fl);
        const float* fp = &F[px * 132];
#pragma unroll 8
        for (int c = 0; c < 128; c += 4) {
            float4 fv = *reinterpret_cast<const float4*>(fp + c);
            a += fv.x * cw[c * 16 + j] + fv.y * cw[(c + 1) * 16 + j]
               + fv.z * cw[(c + 2) * 16 + j] + fv.w * cw[(c + 3) * 16 + j];
        }
        float m = a;
#pragma unroll
        for (int s = 8; s > 0; s >>= 1) m = fmaxf(m, __shfl_xor(m, s, 16));
        float e = expf(a - m);
        float d = e;
#pragma unroll
        for (int s = 8; s > 0; s >>= 1) d += __shfl_xor(d, s, 16);
        float r = e / d;
        long oi = (long)(blockIdx.x * 8 + px) * 16 + j;
        if (fl) ((float*)out)[oi] = r;
        else ((bf16*)out)[oi] = __float2bfloat16(r);
    }
}

// ---------------- attention (4 rows/block) + stats + optional last-block fold of NEXT layer ----------------
template <int MODE>
__global__ __launch_bounds__(256) void attn_fused_kernel(
        const float* __restrict__ th, const float* __restrict__ outm,
        const int* __restrict__ nbr, float* __restrict__ dst, int co,
        float* __restrict__ H2b, float2* __restrict__ partP, float2* __restrict__ partS, int snp,
        int* cnt, int nblk, const int* dflag,
        const float2* fpA, int fnpA, int fsplit, const float2* fpB, int fnpB,
        int fCI, float fPinv, const void* fg, const void* fb,
        const void* fW1, const void* fb1, int fCo1, int fw1f32,
        const void* fW2, const void* fb2, int fCo2,
        float* fWF1, float* fBF1, float* fWF2, float* fBF2) {
    int wid = threadIdx.x >> 6, l = threadIdx.x & 63;
    int n = blockIdx.x * 4 + wid;
    float r0 = th[(long)n * 128 + l];
    float r1 = th[(long)n * 128 + 64 + l];
    int mk[KNB];
    float av[KNB];
#pragma unroll
    for (int k = 0; k < KNB; k++) {
        int m = nbr[n * KNB + k];
        mk[k] = m;
        float v = r0 * th[(long)m * 128 + l] + r1 * th[(long)m * 128 + 64 + l];
#pragma unroll
        for (int off = 32; off > 0; off >>= 1) v += __shfl_xor(v, off, 64);
        av[k] = 1.f / (1.f + expf(-v));
    }
    float amax = av[0];
#pragma unroll
    for (int k = 1; k < KNB; k++) amax = fmaxf(amax, av[k]);
    float den = 0.f;
#pragma unroll
    for (int k = 0; k < KNB; k++) { av[k] = expf(av[k] - amax); den += av[k]; }
    float rden = 1.f / den;
    float val = 0.f;
    if (l < co) {
        float acc = 0.f;
#pragma unroll
        for (int k = 0; k < KNB; k++) acc += av[k] * outm[(long)mk[k] * co + l];
        val = leaky(acc * rden);
        dst[(long)n * co + l] = val;
    }
    __shared__ float sm[4][64];
    sm[wid][l] = (l < co) ? val : 0.f;
    __syncthreads();
    if (wid == 0 && l < co) {
        float a = sm[0][l], bb = sm[1][l], c = sm[2][l], d = sm[3][l];
        float su = a + bb + c + d;
        float sq = a * a + bb * bb + c * c + d * d;
        if (MODE == 0) {
            float h = 0.25f * su;
            H2b[(long)blockIdx.x * 64 + l] = h;
            partP[(long)l * snp + blockIdx.x] = make_float2(h, h * h);
            partS[(long)l * snp + blockIdx.x] = make_float2(su, sq);
        } else {
            partS[(long)l * snp + blockIdx.x] = make_float2(4.f * su, 4.f * sq);
        }
    }
    __shared__ int lastf;
    if (!last_block(cnt, nblk, &lastf)) return;
    __shared__ float al[256], be[256];
    int fl = *dflag;
    fold_layer(fpA, fnpA, fsplit, fpB, fnpB, fCI, fPinv, fg, fb, fl,
               fW1, fb1, fCo1, fw1f32, fW2, fb2, fCo2, fWF1, fBF1, fWF2, fBF2, al, be);
}

// ================= host side =================
extern "C" void kernel_launch(void* const* d_in, const int* in_sizes, int n_in,
                              void* d_out, int out_size, void* d_ws, size_t ws_size,
                              hipStream_t stream) {
    bool dict = (in_sizes[1] > 1000000);
    int I_x, I_nbr_a, I_nbr_b, I_hg, I_ws, I_e0, I_e1, I_d0, I_tg;
    if (dict) {
        I_x = 0; I_nbr_a = 5; I_nbr_b = 6; I_hg = 7; I_e0 = 13; I_e1 = 19; I_d0 = 25; I_tg = 31; I_ws = 37;
    } else {
        I_x = 0; I_hg = 1; I_e0 = 7; I_e1 = 13; I_d0 = 19; I_tg = 25; I_ws = 31; I_nbr_a = 37; I_nbr_b = 38;
    }
    const void* x    = d_in[I_x];
    const int* nbr_a = (const int*)d_in[I_nbr_a];
    const int* nbr_b = (const int*)d_in[I_nbr_b];
    const void* hg   = d_in[I_hg + 0];
    const void* hb   = d_in[I_hg + 1];
    const void* hpw  = d_in[I_hg + 2];
    const void* hpb  = d_in[I_hg + 3];
    const void* hdw  = d_in[I_hg + 4];
    const void* hdb  = d_in[I_hg + 5];
    const void* e0_g = d_in[I_e0 + 0];
    const void* e0_b = d_in[I_e0 + 1];
    const void* e0_wt= d_in[I_e0 + 2];
    const void* e0_bt= d_in[I_e0 + 3];
    const void* e0_wo= d_in[I_e0 + 4];
    const void* e0_bo= d_in[I_e0 + 5];
    const void* e1_g = d_in[I_e1 + 0];
    const void* e1_b = d_in[I_e1 + 1];
    const void* e1_wt= d_in[I_e1 + 2];
    const void* e1_bt= d_in[I_e1 + 3];
    const void* e1_wo= d_in[I_e1 + 4];
    const void* e1_bo= d_in[I_e1 + 5];
    const void* d0_g = d_in[I_d0 + 0];
    const void* d0_b = d_in[I_d0 + 1];
    const void* d0_wt= d_in[I_d0 + 2];
    const void* d0_bt= d_in[I_d0 + 3];
    const void* d0_wo= d_in[I_d0 + 4];
    const void* d0_bo= d_in[I_d0 + 5];
    const void* tg   = d_in[I_tg + 0];
    const void* tb   = d_in[I_tg + 1];
    const void* tpw  = d_in[I_tg + 2];
    const void* tpb  = d_in[I_tg + 3];
    const void* tdw  = d_in[I_tg + 4];
    const void* tdb  = d_in[I_tg + 5];
    const void* wsw  = d_in[I_ws + 0];
    const void* wb   = d_in[I_ws + 1];

    float* W = (float*)d_ws;
    float*  WHc   = W + 0;        // 200*128 = 25600
    float*  WTc   = W + 25600;    // 192*128 = 24576 -> 50176
    int*    dflag = (int*)(W + 50176);
    int*    cnts  = (int*)(W + 50240);   // 8 ints
    float*  WFh   = W + 50304;    // 25600 -> 75904
    float*  BFh   = W + 75904;    // 128   -> 76032
    float*  WF1e0 = W + 76032;    // 16384 -> 92416
    float*  BF1e0 = W + 92416;    // 128   -> 92544
    float*  WF2e0 = W + 92544;    // 8192  -> 100736
    float*  BF2e0 = W + 100736;   // 64    -> 100800
    float*  WF1e1 = W + 100800;   // 8192  -> 108992
    float*  BF1e1 = W + 108992;   // 128   -> 109120
    float*  WF2e1 = W + 109120;   // 2048  -> 111168
    float*  BF2e1 = W + 111168;   // 32    -> 111200
    float*  WF1d0 = W + 111200;   // 12288 -> 123488
    float*  BF1d0 = W + 123488;   // 128   -> 123616
    float*  WF2d0 = W + 123616;   // 6144  -> 129760
    float*  BF2d0 = W + 129760;   // 64    -> 129824
    float*  WFt   = W + 129824;   // 24576 -> 154400
    float*  BFt   = W + 154400;   // 128   -> 154528
    float2* P_HEAD = (float2*)(W + 154528);  // 200*256 f2 -> 256928
    float2* P_E0   = (float2*)(W + 256928);  // 128*512 f2 -> 388000
    float2* P_Tb   = (float2*)(W + 388000);  // 128*512 f2 -> 519072
    float2* P_E1   = (float2*)(W + 519072);  // 64*1024 f2 -> 650144
    float2* P_D0a  = (float2*)(W + 650144);  // 32*256 f2  -> 666528
    float2* P_D0b  = (float2*)(W + 666528);  // 64*1024 f2 -> 797600
    float2* P_Ta   = (float2*)(W + 797600);  // 64*1024 f2 -> 928672
    float*  R0    = W + 928672;              // 16384*128
    float*  R1    = R0 + (long)N0 * 128;     // enc0
    float*  T1    = R1 + (long)N0 * 128;
    float*  H1b   = T1 + (long)N0 * 128;
    float*  THb   = H1b + (long)N1 * 128;
    float*  OUTb  = THb + (long)N1 * 128;
    float*  ENC1  = OUTb + (long)N1 * 64;
    float*  H2b   = ENC1 + (long)N1 * 64;
    float*  HDb   = H2b + (long)N2 * 64;
    float*  HDEC  = HDb + (long)N2 * 32;

    // K0. prep: detect + zero counters + transpose head/tail 1x1 weights
    prep_kernel<<<16, 256, 0, stream>>>(x, hpw, tpw, WHc, WTc, dflag, cnts);
    // K1. head BN stage A + last-block head fold
    bnx_kernel<<<256, 256, 0, stream>>>(x, P_HEAD, WHc, hpb, hg, hb, WFh, BFh, &cnts[0]);
    // K2. head pointwise GEMM + leaky
    gemmT_head_kernel<<<1024, 256, 0, stream>>>(x, WFh, BFh, R0, dflag);
    // K3. head dw + pool4 + stats + last-block e0 fold
    dwpool_kernel<<<512, 256, 0, stream>>>(R0, hdw, hdb, R1, H1b, P_E0, P_Tb, dflag,
                                           e0_wt, e0_bt, e0_wo, e0_bo, e0_g, e0_b,
                                           WF1e0, BF1e0, WF2e0, BF2e0, &cnts[1]);
    // K4. e0 theta+out GEMMs
    gemm2_f32_kernel<<<768, 256, 0, stream>>>(H1b, WF1e0, BF1e0, THb, 128,
                                              WF2e0, BF2e0, OUTb, 64, 128, 512);
    // K5. e0 attention -> ENC1 (+H2b, e1/d0 stats) + last-block e1 fold
    attn_fused_kernel<0><<<1024, 256, 0, stream>>>(THb, OUTb, nbr_a, ENC1, 64, H2b, P_E1, P_D0b, 1024,
        &cnts[2], 1024, dflag, P_E1, 1024, 64, P_E1, 1024, 64, 1.f / (float)N2, e1_g, e1_b,
        e1_wt, e1_bt, 128, 0, e1_wo, e1_bo, 32, WF1e1, BF1e1, WF2e1, BF2e1);
    // K6. e1 GEMMs
    gemm2_f32_kernel<<<160, 256, 0, stream>>>(H2b, WF1e1, BF1e1, THb, 128,
                                              WF2e1, BF2e1, OUTb, 32, 64, 128);
    // K7. e1 attention -> HDb (+d0 stats) + last-block d0 fold
    attn_fused_kernel<1><<<256, 256, 0, stream>>>(THb, OUTb, nbr_b, HDb, 32, nullptr, nullptr, P_D0a, 256,
        &cnts[3], 256, dflag, P_D0a, 256, 32, P_D0b, 1024, 96, 1.f / (float)N1, d0_g, d0_b,
        d0_wt, d0_bt, 128, 0, d0_wo, d0_bo, 64, WF1d0, BF1d0, WF2d0, BF2d0);
    // K8. d0 GEMMs on virtual concat [HDb | ENC1]
    gemm2cat_kernel<32><<<768, 256, 0, stream>>>(HDb, 32, ENC1, 64,
                                                 WF1d0, BF1d0, THb, 128,
                                                 WF2d0, BF2d0, OUTb, 64, 96, 512);
    // K9. d0 attention -> HDEC (+tail stats) + last-block tail fold
    attn_fused_kernel<2><<<1024, 256, 0, stream>>>(THb, OUTb, nbr_a, HDEC, 64, nullptr, nullptr, P_Ta, 1024,
        &cnts[4], 1024, dflag, P_Ta, 1024, 64, P_Tb, 512, 192, 1.f / (float)N0, tg, tb,
        WTc, tpb, 128, 1, nullptr, nullptr, 0, WFt, BFt, nullptr, nullptr);
    // K10. tail pointwise GEMM + leaky on virtual concat [HDEC | enc0]
    gemmT_tail_kernel<<<1024, 256, 0, stream>>>(R1, HDEC, WFt, BFt, T1);
    // K11. tail dw + classifier + softmax
    dwcls_kernel<<<2048, 256, 0, stream>>>(T1, tdw, tdb, wsw, wb, d_out, dflag);
}

// Round 7
// 840.398 us; speedup vs baseline: 1.4385x; 1.4385x over previous
//
#include <hip/hip_runtime.h>
#include <hip/hip_bf16.h>
#include <math.h>

using bf16 = __hip_bfloat16;

#define H_IMG 128
#define W_IMG 128
#define C_IN  200
#define NCLS  16
#define N0    16384
#define N1    4096
#define N2    1024
#define KNB   16
#define EPS   1e-5f
#define SLOPE 0.01f

__device__ __forceinline__ float ldf(const float* p, long i) { return p[i]; }
__device__ __forceinline__ float ldf(const bf16* p, long i) { return __bfloat162float(p[i]); }
__device__ __forceinline__ float leaky(float v) { return v >= 0.f ? v : SLOPE * v; }

__device__ __forceinline__ float4 ld4(const float* p, long i) {
    return *reinterpret_cast<const float4*>(p + i);
}
__device__ __forceinline__ float4 ld4(const bf16* p, long i) {
    const ushort4 u = *reinterpret_cast<const ushort4*>(reinterpret_cast<const unsigned short*>(p) + i);
    float4 r;
    r.x = __uint_as_float((unsigned)u.x << 16);
    r.y = __uint_as_float((unsigned)u.y << 16);
    r.z = __uint_as_float((unsigned)u.z << 16);
    r.w = __uint_as_float((unsigned)u.w << 16);
    return r;
}

// ---------- dtype detector: underlying fp32 read as bf16 stream shows wild exponents ----------
__global__ void detect_kernel(const unsigned short* __restrict__ x, int* __restrict__ flag) {
    int t = threadIdx.x; // 64
    int cnt = 0;
    for (int i = t; i < 4096; i += 64) {
        unsigned short e = (unsigned short)((x[i] >> 7) & 0xFF);
        if (e >= 0xC0) cnt++;
    }
#pragma unroll
    for (int off = 32; off > 0; off >>= 1) cnt += __shfl_xor(cnt, off, 64);
    if (t == 0) *flag = (cnt > 32) ? 1 : 0;
}

// ---------------- BN stats: stage A (coalesced row-major partial sums) ----------------
// part layout: part[c*256 + b] sums, part[65536 + c*256 + b] sumsq
template <typename TX>
__device__ __forceinline__ void bnA_body(const TX* __restrict__ X, int P, int C, float* __restrict__ part) {
    int b = blockIdx.x;   // 256 blocks
    int t = threadIdx.x;  // 256 threads, thread t = channel t
    int rpb = P >> 8;     // P/256 rows per block
    if (t < C) {
        float s = 0.f, s2 = 0.f;
        long base = (long)b * rpb * C + t;
        for (int r = 0; r < rpb; r++) {
            float v = ldf(X, base + (long)r * C);
            s += v; s2 += v * v;
        }
        part[(long)t * 256 + b] = s;
        part[65536 + (long)t * 256 + b] = s2;
    }
}

__global__ __launch_bounds__(256) void bnA_kernel(const void* X, int P, int C, float* part,
                                                  const int* flag, int xraw) {
    if (*flag || !xraw) bnA_body<float>((const float*)X, P, C, part);
    else bnA_body<bf16>((const bf16*)X, P, C, part);
}

// ---------------- BN stats: stage B (reduce 256 partials per channel -> alpha/beta) ----------------
__global__ __launch_bounds__(256) void bnB_kernel(const float* __restrict__ part, int P,
                                                  const void* g, const void* b_,
                                                  float* __restrict__ alpha, float* __restrict__ beta,
                                                  const int* flag) {
    int c = blockIdx.x;
    int t = threadIdx.x;
    __shared__ float rs[256], rq[256];
    rs[t] = part[(long)c * 256 + t];
    rq[t] = part[65536 + (long)c * 256 + t];
    __syncthreads();
    for (int k = 128; k > 0; k >>= 1) {
        if (t < k) { rs[t] += rs[t + k]; rq[t] += rq[t + k]; }
        __syncthreads();
    }
    if (t == 0) {
        float mu = rs[0] / (float)P;
        float var = rq[0] / (float)P - mu * mu;
        float gv = *flag ? ((const float*)g)[c] : __bfloat162float(((const bf16*)g)[c]);
        float bv = *flag ? ((const float*)b_)[c] : __bfloat162float(((const bf16*)b_)[c]);
        float a = rsqrtf(var + EPS) * gv;
        alpha[c] = a;
        beta[c] = bv - mu * a;
    }
}

// ---------------- fold BN into weights ----------------
template <typename TW>
__device__ __forceinline__ void fold_body(const TW* __restrict__ W, const TW* __restrict__ bias,
                                          const float* __restrict__ alpha, const float* __restrict__ beta,
                                          float* __restrict__ Wf, float* __restrict__ Bf,
                                          int Ci, int Co, int omajor, int j) {
    int t = threadIdx.x;
    float acc = 0.f;
    for (int c = t; c < Ci; c += 256) {
        float w = omajor ? ldf(W, (long)j * Ci + c) : ldf(W, (long)c * Co + j);
        Wf[(long)c * Co + j] = w * alpha[c];
        acc += w * beta[c];
    }
    __shared__ float red[256];
    red[t] = acc; __syncthreads();
    for (int k = 128; k > 0; k >>= 1) { if (t < k) red[t] += red[t + k]; __syncthreads(); }
    if (t == 0) Bf[j] = ldf(bias, (long)j) + red[0];
}

__global__ __launch_bounds__(256) void fold_kernel(const void* W, const void* bias,
                                                   const float* alpha, const float* beta,
                                                   float* Wf, float* Bf, int Ci, int Co, int omajor,
                                                   const int* flag) {
    if (*flag) fold_body<float>((const float*)W, (const float*)bias, alpha, beta, Wf, Bf, Ci, Co, omajor, blockIdx.x);
    else fold_body<bf16>((const bf16*)W, (const bf16*)bias, alpha, beta, Wf, Bf, Ci, Co, omajor, blockIdx.x);
}

// fused fold of two weight matrices sharing alpha/beta (GCN wt + wo, both c-major)
__global__ __launch_bounds__(256) void fold2_kernel(const void* W1, const void* b1,
                                                    const void* W2, const void* b2,
                                                    const float* alpha, const float* beta,
                                                    float* Wf1, float* Bf1, float* Wf2, float* Bf2,
                                                    int Ci, int Co1, int Co2, const int* flag) {
    int j = blockIdx.x;
    if (*flag) {
        if (j < Co1) fold_body<float>((const float*)W1, (const float*)b1, alpha, beta, Wf1, Bf1, Ci, Co1, 0, j);
        else fold_body<float>((const float*)W2, (const float*)b2, alpha, beta, Wf2, Bf2, Ci, Co2, 0, j - Co1);
    } else {
        if (j < Co1) fold_body<bf16>((const bf16*)W1, (const bf16*)b1, alpha, beta, Wf1, Bf1, Ci, Co1, 0, j);
        else fold_body<bf16>((const bf16*)W2, (const bf16*)b2, alpha, beta, Wf2, Bf2, Ci, Co2, 0, j - Co1);
    }
}

// ---------------- GEMM: Out[n, j4..j4+3] = act(sum_c In[n,c]*Wf[c,j] + Bf[j]) ----------------
// float4 both sides: 4 outputs/thread, K unrolled by 4 -> 5 VMEM per 16 FMA
template <typename T, int ACT>
__device__ __forceinline__ void gemm4_body(const T* __restrict__ In, const float* __restrict__ Wf,
                                           const float* __restrict__ Bf, float* __restrict__ Out,
                                           int Ci, int Co, int blk) {
    int tid = blk * 256 + threadIdx.x;
    int Coq = Co >> 2;
    int n = tid / Coq;
    int j4 = (tid - n * Coq) << 2;
    const T* in = In + (long)n * Ci;
    const float* wp = Wf + j4;
    float4 acc = *reinterpret_cast<const float4*>(Bf + j4);
    for (int c = 0; c < Ci; c += 4) {
        float4 xv = ld4(in, c);
        float4 w0 = *reinterpret_cast<const float4*>(wp + (long)c * Co);
        float4 w1 = *reinterpret_cast<const float4*>(wp + (long)(c + 1) * Co);
        float4 w2 = *reinterpret_cast<const float4*>(wp + (long)(c + 2) * Co);
        float4 w3 = *reinterpret_cast<const float4*>(wp + (long)(c + 3) * Co);
        acc.x += xv.x * w0.x; acc.y += xv.x * w0.y; acc.z += xv.x * w0.z; acc.w += xv.x * w0.w;
        acc.x += xv.y * w1.x; acc.y += xv.y * w1.y; acc.z += xv.y * w1.z; acc.w += xv.y * w1.w;
        acc.x += xv.z * w2.x; acc.y += xv.z * w2.y; acc.z += xv.z * w2.z; acc.w += xv.z * w2.w;
        acc.x += xv.w * w3.x; acc.y += xv.w * w3.y; acc.z += xv.w * w3.z; acc.w += xv.w * w3.w;
    }
    if (ACT) { acc.x = leaky(acc.x); acc.y = leaky(acc.y); acc.z = leaky(acc.z); acc.w = leaky(acc.w); }
    *reinterpret_cast<float4*>(Out + (long)n * Co + j4) = acc;
}

// head GEMM: In is raw input (dtype dynamic)
__global__ __launch_bounds__(256) void gemm4_dyn_kernel(const void* In, const float* Wf, const float* Bf,
                                                        float* Out, int Ci, int Co, const int* flag) {
    if (*flag) gemm4_body<float, 1>((const float*)In, Wf, Bf, Out, Ci, Co, blockIdx.x);
    else gemm4_body<bf16, 1>((const bf16*)In, Wf, Bf, Out, Ci, Co, blockIdx.x);
}

template <int ACT>
__global__ __launch_bounds__(256) void gemm4_f32_kernel(const float* In, const float* Wf, const float* Bf,
                                                        float* Out, int Ci, int Co) {
    gemm4_body<float, ACT>(In, Wf, Bf, Out, Ci, Co, blockIdx.x);
}

// fused pair of GEMMs sharing the input (GCN theta + out projections)
template <int ACT>
__global__ __launch_bounds__(256) void gemm2_f32_kernel(const float* In,
                                                        const float* W1, const float* B1, float* O1, int Co1,
                                                        const float* W2, const float* B2, float* O2, int Co2,
                                                        int Ci, int nb1) {
    int b = blockIdx.x;
    if (b < nb1) gemm4_body<float, ACT>(In, W1, B1, O1, Ci, Co1, b);
    else gemm4_body<float, ACT>(In, W2, B2, O2, Ci, Co2, b - nb1);
}

// ---------------- depthwise 5x5 SAME + bias + leaky: 4 channels/thread, weights in LDS ----------------
template <typename TW>
__device__ __forceinline__ void dw4_body(const float* __restrict__ In, const TW* __restrict__ dwp,
                                         const TW* __restrict__ dbp, float* __restrict__ Out) {
    __shared__ float wl[25][128];
    __shared__ float bl[128];
    int t = threadIdx.x;
    for (int e = t; e < 25 * 128; e += 256) {
        int o = e / 25, i = e - o * 25;
        wl[i][o] = ldf(dwp, e);   // dwp layout [o][25]; transpose into [tap][channel]
    }
    if (t < 128) bl[t] = ldf(dbp, (long)t);
    __syncthreads();

    int tid = blockIdx.x * 256 + t;    // 16384 pixels * 32 channel-quads
    int o0 = (tid & 31) << 2;
    int p = tid >> 5;
    int h = p >> 7, w = p & 127;
    float4 acc = *reinterpret_cast<const float4*>(&bl[o0]);
#pragma unroll
    for (int dh = -2; dh <= 2; dh++) {
        int hh = h + dh;
        if ((unsigned)hh >= (unsigned)H_IMG) continue;
#pragma unroll
        for (int dv = -2; dv <= 2; dv++) {
            int ww = w + dv;
            if ((unsigned)ww >= (unsigned)W_IMG) continue;
            float4 iv = *reinterpret_cast<const float4*>(&In[(long)(((hh << 7) + ww) << 7) + o0]);
            float4 wv = *reinterpret_cast<const float4*>(&wl[(dh + 2) * 5 + (dv + 2)][o0]);
            acc.x += iv.x * wv.x; acc.y += iv.y * wv.y; acc.z += iv.z * wv.z; acc.w += iv.w * wv.w;
        }
    }
    acc.x = leaky(acc.x); acc.y = leaky(acc.y); acc.z = leaky(acc.z); acc.w = leaky(acc.w);
    *reinterpret_cast<float4*>(&Out[(long)p * 128 + o0]) = acc;
}

__global__ __launch_bounds__(256) void dw4_kernel(const float* In, const void* dwp, const void* dbp,
                                                  float* Out, const int* flag) {
    if (*flag) dw4_body<float>(In, (const float*)dwp, (const float*)dbp, Out);
    else dw4_body<bf16>(In, (const bf16*)dwp, (const bf16*)dbp, Out);
}

// ---------------- avg-pool of 4 consecutive rows (Shat @ H), float4 ----------------
__global__ __launch_bounds__(256) void pool4_kernel(const float* __restrict__ In, float* __restrict__ Out, int F) {
    int tid = blockIdx.x * 256 + threadIdx.x;   // Nout * F/4
    int Fq = F >> 2;
    int j = tid / Fq;
    int f4 = (tid - j * Fq) << 2;
    const float* base = In + (long)(4 * j) * F + f4;
    float4 a = *reinterpret_cast<const float4*>(base);
    float4 b = *reinterpret_cast<const float4*>(base + F);
    float4 c = *reinterpret_cast<const float4*>(base + 2 * F);
    float4 d = *reinterpret_cast<const float4*>(base + 3 * F);
    float4 r;
    r.x = 0.25f * (a.x + b.x + c.x + d.x);
    r.y = 0.25f * (a.y + b.y + c.y + d.y);
    r.z = 0.25f * (a.z + b.z + c.z + d.z);
    r.w = 0.25f * (a.w + b.w + c.w + d.w);
    *reinterpret_cast<float4*>(Out + (long)j * F + f4) = r;
}

// ---------------- GCN attention: 4 rows per block (1 row per wave) ----------------
__global__ __launch_bounds__(256) void attn_kernel(const float* __restrict__ th, const float* __restrict__ outm,
                                                   const int* __restrict__ nbr, float* __restrict__ dst, int co) {
    int n = blockIdx.x * 4 + (threadIdx.x >> 6);
    int l = threadIdx.x & 63;
    float r0 = th[(long)n * 128 + l];
    float r1 = th[(long)n * 128 + 64 + l];
    int mk[KNB];
    float av[KNB];
#pragma unroll
    for (int k = 0; k < KNB; k++) {
        int m = nbr[n * KNB + k];
        mk[k] = m;
        float v = r0 * th[(long)m * 128 + l] + r1 * th[(long)m * 128 + 64 + l];
#pragma unroll
        for (int off = 32; off > 0; off >>= 1) v += __shfl_xor(v, off, 64);
        av[k] = 1.f / (1.f + expf(-v));
    }
    float amax = av[0];
#pragma unroll
    for (int k = 1; k < KNB; k++) amax = fmaxf(amax, av[k]);
    float den = 0.f;
#pragma unroll
    for (int k = 0; k < KNB; k++) { av[k] = expf(av[k] - amax); den += av[k]; }
    float rden = 1.f / den;
    if (l < co) {
        float acc = 0.f;
#pragma unroll
        for (int k = 0; k < KNB; k++) acc += av[k] * outm[(long)mk[k] * co + l];
        dst[(long)n * co + l] = leaky(acc * rden);
    }
}

// ---------------- concats (float4) ----------------
__global__ __launch_bounds__(256) void concat_hcat_kernel(const float* __restrict__ Hd, const float* __restrict__ enc1,
                                                          float* __restrict__ Hcat) {
    int tid = blockIdx.x * 256 + threadIdx.x; // 4096 * 24 quads
    int n = tid / 24;
    int f4 = (tid - n * 24) << 2;
    float4 v;
    if (f4 < 32) v = *reinterpret_cast<const float4*>(&Hd[(long)(n >> 2) * 32 + f4]);
    else v = *reinterpret_cast<const float4*>(&enc1[(long)n * 64 + (f4 - 32)]);
    *reinterpret_cast<float4*>(&Hcat[(long)n * 96 + f4]) = v;
}

__global__ __launch_bounds__(256) void concat_g_kernel(const float* __restrict__ Hdec, const float* __restrict__ H0,
                                                       float* __restrict__ G) {
    int tid = blockIdx.x * 256 + threadIdx.x; // 16384 * 48 quads
    int p = tid / 48;
    int f4 = (tid - p * 48) << 2;
    float4 v;
    if (f4 < 64) v = *reinterpret_cast<const float4*>(&Hdec[(long)(p >> 2) * 64 + f4]);
    else v = *reinterpret_cast<const float4*>(&H0[(long)p * 128 + (f4 - 64)]);
    *reinterpret_cast<float4*>(&G[(long)p * 192 + f4]) = v;
}

// ---------------- classifier: weights in LDS, float4 feature loads ----------------
template <typename TW>
__device__ __forceinline__ void cls_body(const float* __restrict__ F, const TW* __restrict__ wsw,
                                         const TW* __restrict__ wb, TW* __restrict__ out) {
    __shared__ float wl[128 * 16];
    int t = threadIdx.x;
    for (int e = t; e < 2048; e += 256) wl[e] = ldf(wsw, (long)e);
    __syncthreads();
    int tid = blockIdx.x * 256 + t; // 16384*16
    int p = tid >> 4;
    int j = tid & 15;
    float acc = ldf(wb, (long)j);
    const float* fp = F + (long)p * 128;
#pragma unroll 8
    for (int c = 0; c < 128; c += 4) {
        float4 fv = *reinterpret_cast<const float4*>(fp + c);
        acc += fv.x * wl[c * 16 + j] + fv.y * wl[(c + 1) * 16 + j]
             + fv.z * wl[(c + 2) * 16 + j] + fv.w * wl[(c + 3) * 16 + j];
    }
    float m = acc;
#pragma unroll
    for (int s = 8; s > 0; s >>= 1) m = fmaxf(m, __shfl_xor(m, s, 16));
    float e = expf(acc - m);
    float d = e;
#pragma unroll
    for (int s = 8; s > 0; s >>= 1) d += __shfl_xor(d, s, 16);
    float r = e / d;
    if constexpr (sizeof(TW) == 2) out[tid] = __float2bfloat16(r);
    else out[tid] = r;
}

__global__ __launch_bounds__(256) void cls_kernel(const float* F, const void* wsw, const void* wb,
                                                  void* out, const int* flag) {
    if (*flag) cls_body<float>(F, (const float*)wsw, (const float*)wb, (float*)out);
    else cls_body<bf16>(F, (const bf16*)wsw, (const bf16*)wb, (bf16*)out);
}

// ================= host side =================
extern "C" void kernel_launch(void* const* d_in, const int* in_sizes, int n_in,
                              void* d_out, int out_size, void* d_ws, size_t ws_size,
                              hipStream_t stream) {
    bool dict = (in_sizes[1] > 1000000);
    int I_x, I_nbr_a, I_nbr_b, I_hg, I_ws, I_e0, I_e1, I_d0, I_tg;
    if (dict) {
        I_x = 0; I_nbr_a = 5; I_nbr_b = 6; I_hg = 7; I_e0 = 13; I_e1 = 19; I_d0 = 25; I_tg = 31; I_ws = 37;
    } else {
        I_x = 0; I_hg = 1; I_e0 = 7; I_e1 = 13; I_d0 = 19; I_tg = 25; I_ws = 31; I_nbr_a = 37; I_nbr_b = 38;
    }
    const void* x    = d_in[I_x];
    const int* nbr_a = (const int*)d_in[I_nbr_a];
    const int* nbr_b = (const int*)d_in[I_nbr_b];
    const void* hg   = d_in[I_hg + 0];
    const void* hb   = d_in[I_hg + 1];
    const void* hpw  = d_in[I_hg + 2];
    const void* hpb  = d_in[I_hg + 3];
    const void* hdw  = d_in[I_hg + 4];
    const void* hdb  = d_in[I_hg + 5];
    const void* e0_g = d_in[I_e0 + 0];
    const void* e0_b = d_in[I_e0 + 1];
    const void* e0_wt= d_in[I_e0 + 2];
    const void* e0_bt= d_in[I_e0 + 3];
    const void* e0_wo= d_in[I_e0 + 4];
    const void* e0_bo= d_in[I_e0 + 5];
    const void* e1_g = d_in[I_e1 + 0];
    const void* e1_b = d_in[I_e1 + 1];
    const void* e1_wt= d_in[I_e1 + 2];
    const void* e1_bt= d_in[I_e1 + 3];
    const void* e1_wo= d_in[I_e1 + 4];
    const void* e1_bo= d_in[I_e1 + 5];
    const void* d0_g = d_in[I_d0 + 0];
    const void* d0_b = d_in[I_d0 + 1];
    const void* d0_wt= d_in[I_d0 + 2];
    const void* d0_bt= d_in[I_d0 + 3];
    const void* d0_wo= d_in[I_d0 + 4];
    const void* d0_bo= d_in[I_d0 + 5];
    const void* tg   = d_in[I_tg + 0];
    const void* tb   = d_in[I_tg + 1];
    const void* tpw  = d_in[I_tg + 2];
    const void* tpb  = d_in[I_tg + 3];
    const void* tdw  = d_in[I_tg + 4];
    const void* tdb  = d_in[I_tg + 5];
    const void* wsw  = d_in[I_ws + 0];
    const void* wb   = d_in[I_ws + 1];

    float* W = (float*)d_ws;
    float* AB_a  = W + 0;
    float* AB_b  = W + 256;
    float* WF1   = W + 512;       // up to 200*128
    float* BF1   = W + 33280;
    float* WF2   = W + 33536;     // up to 128*64
    float* BF2   = W + 41728;
    int*   dflag = (int*)(W + 49152);
    float* PART  = W + 49408;     // 2 * 256ch * 256blk = 131072 floats
    float* R0    = W + 196608;         // 16384*192
    float* R1    = R0 + (long)N0*192;  // 16384*128
    float* H1b   = R1 + (long)N0*128;  // 4096*128
    float* THb   = H1b + (long)N1*128; // 4096*128
    float* OUTb  = THb + (long)N1*128; // 4096*64
    float* ENC1  = OUTb + (long)N1*64; // 4096*64
    float* H2b   = ENC1 + (long)N1*64; // 1024*64
    float* HDb   = H2b + (long)N2*64;  // 1024*32
    float* HCAT  = HDb + (long)N2*32;  // 4096*96
    float* HDEC  = HCAT + (long)N1*96; // 4096*64

    detect_kernel<<<1, 64, 0, stream>>>((const unsigned short*)x, dflag);

    // ---- head SSConv ----
    bnA_kernel<<<256, 256, 0, stream>>>(x, N0, C_IN, PART, dflag, 1);
    bnB_kernel<<<C_IN, 256, 0, stream>>>(PART, N0, hg, hb, AB_a, AB_b, dflag);
    fold_kernel<<<128, 256, 0, stream>>>(hpw, hpb, AB_a, AB_b, WF1, BF1, C_IN, 128, 1, dflag);
    gemm4_dyn_kernel<<<(N0 * 128 / 4) / 256, 256, 0, stream>>>(x, WF1, BF1, R0, C_IN, 128, dflag);
    dw4_kernel<<<(N0 * 32) / 256, 256, 0, stream>>>(R0, hdw, hdb, R1, dflag); // R1 = enc0
    pool4_kernel<<<(N1 * 32) / 256, 256, 0, stream>>>(R1, H1b, 128);

    // ---- GCN e0: 128 -> 64 ----
    bnA_kernel<<<256, 256, 0, stream>>>(H1b, N1, 128, PART, dflag, 0);
    bnB_kernel<<<128, 256, 0, stream>>>(PART, N1, e0_g, e0_b, AB_a, AB_b, dflag);
    fold2_kernel<<<192, 256, 0, stream>>>(e0_wt, e0_bt, e0_wo, e0_bo, AB_a, AB_b,
                                          WF1, BF1, WF2, BF2, 128, 128, 64, dflag);
    {
        int nb1 = (N1 * 32) / 256, nb2 = (N1 * 16) / 256; // th (Co=128), out (Co=64)
        gemm2_f32_kernel<0><<<nb1 + nb2, 256, 0, stream>>>(H1b, WF1, BF1, THb, 128,
                                                           WF2, BF2, OUTb, 64, 128, nb1);
    }
    attn_kernel<<<N1 / 4, 256, 0, stream>>>(THb, OUTb, nbr_a, ENC1, 64);
    pool4_kernel<<<(N2 * 16) / 256, 256, 0, stream>>>(ENC1, H2b, 64);

    // ---- GCN e1: 64 -> 32 ----
    bnA_kernel<<<256, 256, 0, stream>>>(H2b, N2, 64, PART, dflag, 0);
    bnB_kernel<<<64, 256, 0, stream>>>(PART, N2, e1_g, e1_b, AB_a, AB_b, dflag);
    fold2_kernel<<<160, 256, 0, stream>>>(e1_wt, e1_bt, e1_wo, e1_bo, AB_a, AB_b,
                                          WF1, BF1, WF2, BF2, 64, 128, 32, dflag);
    {
        int nb1 = (N2 * 32) / 256, nb2 = (N2 * 8) / 256;
        gemm2_f32_kernel<0><<<nb1 + nb2, 256, 0, stream>>>(H2b, WF1, BF1, THb, 128,
                                                           WF2, BF2, OUTb, 32, 64, nb1);
    }
    attn_kernel<<<N2 / 4, 256, 0, stream>>>(THb, OUTb, nbr_b, HDb, 32);

    // ---- decoder GCN d0 ----
    concat_hcat_kernel<<<(N1 * 24) / 256, 256, 0, stream>>>(HDb, ENC1, HCAT);
    bnA_kernel<<<256, 256, 0, stream>>>(HCAT, N1, 96, PART, dflag, 0);
    bnB_kernel<<<96, 256, 0, stream>>>(PART, N1, d0_g, d0_b, AB_a, AB_b, dflag);
    fold2_kernel<<<192, 256, 0, stream>>>(d0_wt, d0_bt, d0_wo, d0_bo, AB_a, AB_b,
                                          WF1, BF1, WF2, BF2, 96, 128, 64, dflag);
    {
        int nb1 = (N1 * 32) / 256, nb2 = (N1 * 16) / 256;
        gemm2_f32_kernel<0><<<nb1 + nb2, 256, 0, stream>>>(HCAT, WF1, BF1, THb, 128,
                                                           WF2, BF2, OUTb, 64, 96, nb1);
    }
    attn_kernel<<<N1 / 4, 256, 0, stream>>>(THb, OUTb, nbr_a, HDEC, 64);

    // ---- tail ----
    concat_g_kernel<<<(N0 * 48) / 256, 256, 0, stream>>>(HDEC, R1, R0); // R0 = G
    bnA_kernel<<<256, 256, 0, stream>>>(R0, N0, 192, PART, dflag, 0);
    bnB_kernel<<<192, 256, 0, stream>>>(PART, N0, tg, tb, AB_a, AB_b, dflag);
    fold_kernel<<<128, 256, 0, stream>>>(tpw, tpb, AB_a, AB_b, WF1, BF1, 192, 128, 1, dflag);
    gemm4_f32_kernel<1><<<(N0 * 128 / 4) / 256, 256, 0, stream>>>(R0, WF1, BF1, R1, 192, 128); // R1 = T1
    dw4_kernel<<<(N0 * 32) / 256, 256, 0, stream>>>(R1, tdw, tdb, R0, dflag); // R0 = F
    cls_kernel<<<(N0 * NCLS) / 256, 256, 0, stream>>>(R0, wsw, wb, d_out, dflag);
}

// Round 8
// 835.954 us; speedup vs baseline: 1.4461x; 1.0053x over previous
//
#include <hip/hip_runtime.h>
#include <hip/hip_bf16.h>
#include <math.h>

using bf16 = __hip_bfloat16;

#define H_IMG 128
#define W_IMG 128
#define C_IN  200
#define NCLS  16
#define N0    16384
#define N1    4096
#define N2    1024
#define KNB   16
#define EPS   1e-5f
#define SLOPE 0.01f

__device__ __forceinline__ float ldf(const float* p, long i) { return p[i]; }
__device__ __forceinline__ float ldf(const bf16* p, long i) { return __bfloat162float(p[i]); }
__device__ __forceinline__ float leaky(float v) { return v >= 0.f ? v : SLOPE * v; }

__device__ __forceinline__ float4 ld4(const float* p, long i) {
    return *reinterpret_cast<const float4*>(p + i);
}
__device__ __forceinline__ float4 ld4(const bf16* p, long i) {
    const ushort4 u = *reinterpret_cast<const ushort4*>(reinterpret_cast<const unsigned short*>(p) + i);
    float4 r;
    r.x = __uint_as_float((unsigned)u.x << 16);
    r.y = __uint_as_float((unsigned)u.y << 16);
    r.z = __uint_as_float((unsigned)u.z << 16);
    r.w = __uint_as_float((unsigned)u.w << 16);
    return r;
}

// ---------------- K1: head BN stage A with embedded dtype detect ----------------
// part layout: part[c*256 + b] sums, part[65536 + c*256 + b] sumsq
__global__ __launch_bounds__(256) void bnx_kernel(const void* __restrict__ X, float* __restrict__ part,
                                                  int* __restrict__ dflag) {
    // per-block dtype detect (fp32 read as bf16 stream shows wild exponents)
    __shared__ int cnt_s;
    if (threadIdx.x == 0) cnt_s = 0;
    __syncthreads();
    {
        const unsigned short* xu = (const unsigned short*)X;
        int cnt = 0;
        for (int i = threadIdx.x; i < 4096; i += 256) {
            unsigned short e = (unsigned short)((xu[i] >> 7) & 0xFF);
            if (e >= 0xC0) cnt++;
        }
#pragma unroll
        for (int off = 32; off > 0; off >>= 1) cnt += __shfl_xor(cnt, off, 64);
        if ((threadIdx.x & 63) == 0) atomicAdd(&cnt_s, cnt);
    }
    __syncthreads();
    int fl = (cnt_s > 32) ? 1 : 0;
    if (blockIdx.x == 0 && threadIdx.x == 0) *dflag = fl;

    int b = blockIdx.x, t = threadIdx.x;
    if (t >= C_IN) return;
    float s = 0.f, s2 = 0.f;
    if (fl) {
        const float* p = (const float*)X + (long)b * 64 * C_IN + t;
        for (int r = 0; r < 64; r++) { float v = p[(long)r * C_IN]; s += v; s2 += v * v; }
    } else {
        const bf16* p = (const bf16*)X + (long)b * 64 * C_IN + t;
        for (int r = 0; r < 64; r++) { float v = __bfloat162float(p[(long)r * C_IN]); s += v; s2 += v * v; }
    }
    part[(long)t * 256 + b] = s;
    part[65536 + (long)t * 256 + b] = s2;
}

// ---------------- BN stats stage A for f32 intermediates (unchanged body) ----------------
__global__ __launch_bounds__(256) void bnA_kernel(const float* __restrict__ X, int P, int C,
                                                  float* __restrict__ part) {
    int b = blockIdx.x;
    int t = threadIdx.x;
    int rpb = P >> 8;
    if (t < C) {
        float s = 0.f, s2 = 0.f;
        long base = (long)b * rpb * C + t;
        for (int r = 0; r < rpb; r++) {
            float v = X[base + (long)r * C];
            s += v; s2 += v * v;
        }
        part[(long)t * 256 + b] = s;
        part[65536 + (long)t * 256 + b] = s2;
    }
}

// ---------------- alpha/beta from PART into LDS (per-block recompute, ~2KB L2/thread) ----------------
__device__ __forceinline__ void alphabeta_ld(const float* __restrict__ part, int P, int Ci,
                                             const void* g, const void* b_, int fl,
                                             float* al, float* be) {
    int t = threadIdx.x;
    if (t < Ci) {
        const float4* ps = (const float4*)(part + (long)t * 256);
        const float4* pq = (const float4*)(part + 65536 + (long)t * 256);
        float s = 0.f, q = 0.f;
        for (int i = 0; i < 64; i++) { float4 v = ps[i]; s += v.x + v.y + v.z + v.w; }
        for (int i = 0; i < 64; i++) { float4 v = pq[i]; q += v.x + v.y + v.z + v.w; }
        float mu = s / (float)P;
        float var = q / (float)P - mu * mu;
        float gv = fl ? ((const float*)g)[t] : __bfloat162float(((const bf16*)g)[t]);
        float bv = fl ? ((const float*)b_)[t] : __bfloat162float(((const bf16*)b_)[t]);
        float a = rsqrtf(var + EPS) * gv;
        al[t] = a;
        be[t] = bv - mu * a;
    }
    __syncthreads();
}

// ---------------- fold BN into weights (body unchanged from R7) ----------------
template <typename TW>
__device__ __forceinline__ void fold_body(const TW* __restrict__ W, const TW* __restrict__ bias,
                                          const float* __restrict__ alpha, const float* __restrict__ beta,
                                          float* __restrict__ Wf, float* __restrict__ Bf,
                                          int Ci, int Co, int omajor, int j) {
    int t = threadIdx.x;
    float acc = 0.f;
    for (int c = t; c < Ci; c += 256) {
        float w = omajor ? ldf(W, (long)j * Ci + c) : ldf(W, (long)c * Co + j);
        Wf[(long)c * Co + j] = w * alpha[c];
        acc += w * beta[c];
    }
    __shared__ float red[256];
    red[t] = acc; __syncthreads();
    for (int k = 128; k > 0; k >>= 1) { if (t < k) red[t] += red[t + k]; __syncthreads(); }
    if (t == 0) Bf[j] = ldf(bias, (long)j) + red[0];
}

// fused bnB + fold (one matrix)
__global__ __launch_bounds__(256) void bnfold_kernel(const float* part, int P,
                                                     const void* g, const void* b_,
                                                     const void* W, const void* bias,
                                                     float* Wf, float* Bf, int Ci, int Co, int omajor,
                                                     const int* flag) {
    __shared__ float al[256], be[256];
    int fl = *flag;
    alphabeta_ld(part, P, Ci, g, b_, fl, al, be);
    if (fl) fold_body<float>((const float*)W, (const float*)bias, al, be, Wf, Bf, Ci, Co, omajor, blockIdx.x);
    else fold_body<bf16>((const bf16*)W, (const bf16*)bias, al, be, Wf, Bf, Ci, Co, omajor, blockIdx.x);
}

// fused bnB + fold (two matrices sharing alpha/beta, both c-major)
__global__ __launch_bounds__(256) void bnfold2_kernel(const float* part, int P,
                                                      const void* g, const void* b_,
                                                      const void* W1, const void* b1,
                                                      const void* W2, const void* b2,
                                                      float* Wf1, float* Bf1, float* Wf2, float* Bf2,
                                                      int Ci, int Co1, int Co2, const int* flag) {
    __shared__ float al[256], be[256];
    int fl = *flag;
    alphabeta_ld(part, P, Ci, g, b_, fl, al, be);
    int j = blockIdx.x;
    if (fl) {
        if (j < Co1) fold_body<float>((const float*)W1, (const float*)b1, al, be, Wf1, Bf1, Ci, Co1, 0, j);
        else fold_body<float>((const float*)W2, (const float*)b2, al, be, Wf2, Bf2, Ci, Co2, 0, j - Co1);
    } else {
        if (j < Co1) fold_body<bf16>((const bf16*)W1, (const bf16*)b1, al, be, Wf1, Bf1, Ci, Co1, 0, j);
        else fold_body<bf16>((const bf16*)W2, (const bf16*)b2, al, be, Wf2, Bf2, Ci, Co2, 0, j - Co1);
    }
}

// ---------------- GEMM: Out[n, j4..j4+3] = act(sum_c In[n,c]*Wf[c,j] + Bf[j]) ----------------
template <typename T, int ACT>
__device__ __forceinline__ void gemm4_body(const T* __restrict__ In, const float* __restrict__ Wf,
                                           const float* __restrict__ Bf, float* __restrict__ Out,
                                           int Ci, int Co, int blk) {
    int tid = blk * 256 + threadIdx.x;
    int Coq = Co >> 2;
    int n = tid / Coq;
    int j4 = (tid - n * Coq) << 2;
    const T* in = In + (long)n * Ci;
    const float* wp = Wf + j4;
    float4 acc = *reinterpret_cast<const float4*>(Bf + j4);
    for (int c = 0; c < Ci; c += 4) {
        float4 xv = ld4(in, c);
        float4 w0 = *reinterpret_cast<const float4*>(wp + (long)c * Co);
        float4 w1 = *reinterpret_cast<const float4*>(wp + (long)(c + 1) * Co);
        float4 w2 = *reinterpret_cast<const float4*>(wp + (long)(c + 2) * Co);
        float4 w3 = *reinterpret_cast<const float4*>(wp + (long)(c + 3) * Co);
        acc.x += xv.x * w0.x; acc.y += xv.x * w0.y; acc.z += xv.x * w0.z; acc.w += xv.x * w0.w;
        acc.x += xv.y * w1.x; acc.y += xv.y * w1.y; acc.z += xv.y * w1.z; acc.w += xv.y * w1.w;
        acc.x += xv.z * w2.x; acc.y += xv.z * w2.y; acc.z += xv.z * w2.z; acc.w += xv.z * w2.w;
        acc.x += xv.w * w3.x; acc.y += xv.w * w3.y; acc.z += xv.w * w3.z; acc.w += xv.w * w3.w;
    }
    if (ACT) { acc.x = leaky(acc.x); acc.y = leaky(acc.y); acc.z = leaky(acc.z); acc.w = leaky(acc.w); }
    *reinterpret_cast<float4*>(Out + (long)n * Co + j4) = acc;
}

// head GEMM: In is raw input (dtype dynamic)
__global__ __launch_bounds__(256) void gemm4_dyn_kernel(const void* In, const float* Wf, const float* Bf,
                                                        float* Out, int Ci, int Co, const int* flag) {
    if (*flag) gemm4_body<float, 1>((const float*)In, Wf, Bf, Out, Ci, Co, blockIdx.x);
    else gemm4_body<bf16, 1>((const bf16*)In, Wf, Bf, Out, Ci, Co, blockIdx.x);
}

template <int ACT>
__global__ __launch_bounds__(256) void gemm4_f32_kernel(const float* In, const float* Wf, const float* Bf,
                                                        float* Out, int Ci, int Co) {
    gemm4_body<float, ACT>(In, Wf, Bf, Out, Ci, Co, blockIdx.x);
}

// fused pair of GEMMs sharing the input (GCN theta + out projections)
template <int ACT>
__global__ __launch_bounds__(256) void gemm2_f32_kernel(const float* In,
                                                        const float* W1, const float* B1, float* O1, int Co1,
                                                        const float* W2, const float* B2, float* O2, int Co2,
                                                        int Ci, int nb1) {
    int b = blockIdx.x;
    if (b < nb1) gemm4_body<float, ACT>(In, W1, B1, O1, Ci, Co1, b);
    else gemm4_body<float, ACT>(In, W2, B2, O2, Ci, Co2, b - nb1);
}

// ---------------- depthwise 5x5 SAME + bias + leaky: 4 channels/thread, weights in LDS ----------------
template <typename TW>
__device__ __forceinline__ void dw4_body(const float* __restrict__ In, const TW* __restrict__ dwp,
                                         const TW* __restrict__ dbp, float* __restrict__ Out) {
    __shared__ float wl[25][128];
    __shared__ float bl[128];
    int t = threadIdx.x;
    for (int e = t; e < 25 * 128; e += 256) {
        int o = e / 25, i = e - o * 25;
        wl[i][o] = ldf(dwp, e);   // dwp layout [o][25]; transpose into [tap][channel]
    }
    if (t < 128) bl[t] = ldf(dbp, (long)t);
    __syncthreads();

    int tid = blockIdx.x * 256 + t;    // 16384 pixels * 32 channel-quads
    int o0 = (tid & 31) << 2;
    int p = tid >> 5;
    int h = p >> 7, w = p & 127;
    float4 acc = *reinterpret_cast<const float4*>(&bl[o0]);
#pragma unroll
    for (int dh = -2; dh <= 2; dh++) {
        int hh = h + dh;
        if ((unsigned)hh >= (unsigned)H_IMG) continue;
#pragma unroll
        for (int dv = -2; dv <= 2; dv++) {
            int ww = w + dv;
            if ((unsigned)ww >= (unsigned)W_IMG) continue;
            float4 iv = *reinterpret_cast<const float4*>(&In[(long)(((hh << 7) + ww) << 7) + o0]);
            float4 wv = *reinterpret_cast<const float4*>(&wl[(dh + 2) * 5 + (dv + 2)][o0]);
            acc.x += iv.x * wv.x; acc.y += iv.y * wv.y; acc.z += iv.z * wv.z; acc.w += iv.w * wv.w;
        }
    }
    acc.x = leaky(acc.x); acc.y = leaky(acc.y); acc.z = leaky(acc.z); acc.w = leaky(acc.w);
    *reinterpret_cast<float4*>(&Out[(long)p * 128 + o0]) = acc;
}

__global__ __launch_bounds__(256) void dw4_kernel(const float* In, const void* dwp, const void* dbp,
                                                  float* Out, const int* flag) {
    if (*flag) dw4_body<float>(In, (const float*)dwp, (const float*)dbp, Out);
    else dw4_body<bf16>(In, (const bf16*)dwp, (const bf16*)dbp, Out);
}

// ---------------- avg-pool of 4 consecutive rows (Shat @ H), float4 ----------------
__global__ __launch_bounds__(256) void pool4_kernel(const float* __restrict__ In, float* __restrict__ Out, int F) {
    int tid = blockIdx.x * 256 + threadIdx.x;   // Nout * F/4
    int Fq = F >> 2;
    int j = tid / Fq;
    int f4 = (tid - j * Fq) << 2;
    const float* base = In + (long)(4 * j) * F + f4;
    float4 a = *reinterpret_cast<const float4*>(base);
    float4 b = *reinterpret_cast<const float4*>(base + F);
    float4 c = *reinterpret_cast<const float4*>(base + 2 * F);
    float4 d = *reinterpret_cast<const float4*>(base + 3 * F);
    float4 r;
    r.x = 0.25f * (a.x + b.x + c.x + d.x);
    r.y = 0.25f * (a.y + b.y + c.y + d.y);
    r.z = 0.25f * (a.z + b.z + c.z + d.z);
    r.w = 0.25f * (a.w + b.w + c.w + d.w);
    *reinterpret_cast<float4*>(Out + (long)j * F + f4) = r;
}

// ---------------- GCN attention: 4 rows per block (1 row per wave) ----------------
__global__ __launch_bounds__(256) void attn_kernel(const float* __restrict__ th, const float* __restrict__ outm,
                                                   const int* __restrict__ nbr, float* __restrict__ dst, int co) {
    int n = blockIdx.x * 4 + (threadIdx.x >> 6);
    int l = threadIdx.x & 63;
    float r0 = th[(long)n * 128 + l];
    float r1 = th[(long)n * 128 + 64 + l];
    int mk[KNB];
    float av[KNB];
#pragma unroll
    for (int k = 0; k < KNB; k++) {
        int m = nbr[n * KNB + k];
        mk[k] = m;
        float v = r0 * th[(long)m * 128 + l] + r1 * th[(long)m * 128 + 64 + l];
#pragma unroll
        for (int off = 32; off > 0; off >>= 1) v += __shfl_xor(v, off, 64);
        av[k] = 1.f / (1.f + expf(-v));
    }
    float amax = av[0];
#pragma unroll
    for (int k = 1; k < KNB; k++) amax = fmaxf(amax, av[k]);
    float den = 0.f;
#pragma unroll
    for (int k = 0; k < KNB; k++) { av[k] = expf(av[k] - amax); den += av[k]; }
    float rden = 1.f / den;
    if (l < co) {
        float acc = 0.f;
#pragma unroll
        for (int k = 0; k < KNB; k++) acc += av[k] * outm[(long)mk[k] * co + l];
        dst[(long)n * co + l] = leaky(acc * rden);
    }
}

// ---------------- concats (float4) ----------------
__global__ __launch_bounds__(256) void concat_hcat_kernel(const float* __restrict__ Hd, const float* __restrict__ enc1,
                                                          float* __restrict__ Hcat) {
    int tid = blockIdx.x * 256 + threadIdx.x; // 4096 * 24 quads
    int n = tid / 24;
    int f4 = (tid - n * 24) << 2;
    float4 v;
    if (f4 < 32) v = *reinterpret_cast<const float4*>(&Hd[(long)(n >> 2) * 32 + f4]);
    else v = *reinterpret_cast<const float4*>(&enc1[(long)n * 64 + (f4 - 32)]);
    *reinterpret_cast<float4*>(&Hcat[(long)n * 96 + f4]) = v;
}

__global__ __launch_bounds__(256) void concat_g_kernel(const float* __restrict__ Hdec, const float* __restrict__ H0,
                                                       float* __restrict__ G) {
    int tid = blockIdx.x * 256 + threadIdx.x; // 16384 * 48 quads
    int p = tid / 48;
    int f4 = (tid - p * 48) << 2;
    float4 v;
    if (f4 < 64) v = *reinterpret_cast<const float4*>(&Hdec[(long)(p >> 2) * 64 + f4]);
    else v = *reinterpret_cast<const float4*>(&H0[(long)p * 128 + (f4 - 64)]);
    *reinterpret_cast<float4*>(&G[(long)p * 192 + f4]) = v;
}

// ---------------- classifier: weights in LDS, float4 feature loads ----------------
template <typename TW>
__device__ __forceinline__ void cls_body(const float* __restrict__ F, const TW* __restrict__ wsw,
                                         const TW* __restrict__ wb, TW* __restrict__ out) {
    __shared__ float wl[128 * 16];
    int t = threadIdx.x;
    for (int e = t; e < 2048; e += 256) wl[e] = ldf(wsw, (long)e);
    __syncthreads();
    int tid = blockIdx.x * 256 + t; // 16384*16
    int p = tid >> 4;
    int j = tid & 15;
    float acc = ldf(wb, (long)j);
    const float* fp = F + (long)p * 128;
#pragma unroll 8
    for (int c = 0; c < 128; c += 4) {
        float4 fv = *reinterpret_cast<const float4*>(fp + c);
        acc += fv.x * wl[c * 16 + j] + fv.y * wl[(c + 1) * 16 + j]
             + fv.z * wl[(c + 2) * 16 + j] + fv.w * wl[(c + 3) * 16 + j];
    }
    float m = acc;
#pragma unroll
    for (int s = 8; s > 0; s >>= 1) m = fmaxf(m, __shfl_xor(m, s, 16));
    float e = expf(acc - m);
    float d = e;
#pragma unroll
    for (int s = 8; s > 0; s >>= 1) d += __shfl_xor(d, s, 16);
    float r = e / d;
    if constexpr (sizeof(TW) == 2) out[tid] = __float2bfloat16(r);
    else out[tid] = r;
}

__global__ __launch_bounds__(256) void cls_kernel(const float* F, const void* wsw, const void* wb,
                                                  void* out, const int* flag) {
    if (*flag) cls_body<float>(F, (const float*)wsw, (const float*)wb, (float*)out);
    else cls_body<bf16>(F, (const bf16*)wsw, (const bf16*)wb, (bf16*)out);
}

// ================= host side =================
extern "C" void kernel_launch(void* const* d_in, const int* in_sizes, int n_in,
                              void* d_out, int out_size, void* d_ws, size_t ws_size,
                              hipStream_t stream) {
    bool dict = (in_sizes[1] > 1000000);
    int I_x, I_nbr_a, I_nbr_b, I_hg, I_ws, I_e0, I_e1, I_d0, I_tg;
    if (dict) {
        I_x = 0; I_nbr_a = 5; I_nbr_b = 6; I_hg = 7; I_e0 = 13; I_e1 = 19; I_d0 = 25; I_tg = 31; I_ws = 37;
    } else {
        I_x = 0; I_hg = 1; I_e0 = 7; I_e1 = 13; I_d0 = 19; I_tg = 25; I_ws = 31; I_nbr_a = 37; I_nbr_b = 38;
    }
    const void* x    = d_in[I_x];
    const int* nbr_a = (const int*)d_in[I_nbr_a];
    const int* nbr_b = (const int*)d_in[I_nbr_b];
    const void* hg   = d_in[I_hg + 0];
    const void* hb   = d_in[I_hg + 1];
    const void* hpw  = d_in[I_hg + 2];
    const void* hpb  = d_in[I_hg + 3];
    const void* hdw  = d_in[I_hg + 4];
    const void* hdb  = d_in[I_hg + 5];
    const void* e0_g = d_in[I_e0 + 0];
    const void* e0_b = d_in[I_e0 + 1];
    const void* e0_wt= d_in[I_e0 + 2];
    const void* e0_bt= d_in[I_e0 + 3];
    const void* e0_wo= d_in[I_e0 + 4];
    const void* e0_bo= d_in[I_e0 + 5];
    const void* e1_g = d_in[I_e1 + 0];
    const void* e1_b = d_in[I_e1 + 1];
    const void* e1_wt= d_in[I_e1 + 2];
    const void* e1_bt= d_in[I_e1 + 3];
    const void* e1_wo= d_in[I_e1 + 4];
    const void* e1_bo= d_in[I_e1 + 5];
    const void* d0_g = d_in[I_d0 + 0];
    const void* d0_b = d_in[I_d0 + 1];
    const void* d0_wt= d_in[I_d0 + 2];
    const void* d0_bt= d_in[I_d0 + 3];
    const void* d0_wo= d_in[I_d0 + 4];
    const void* d0_bo= d_in[I_d0 + 5];
    const void* tg   = d_in[I_tg + 0];
    const void* tb   = d_in[I_tg + 1];
    const void* tpw  = d_in[I_tg + 2];
    const void* tpb  = d_in[I_tg + 3];
    const void* tdw  = d_in[I_tg + 4];
    const void* tdb  = d_in[I_tg + 5];
    const void* wsw  = d_in[I_ws + 0];
    const void* wb   = d_in[I_ws + 1];

    float* W = (float*)d_ws;
    float* WF1   = W + 512;       // up to 200*128
    float* BF1   = W + 33280;
    float* WF2   = W + 33536;     // up to 128*64
    float* BF2   = W + 41728;
    int*   dflag = (int*)(W + 49152);
    float* PART  = W + 49408;     // 2 * 256ch * 256blk = 131072 floats
    float* R0    = W + 196608;         // 16384*192
    float* R1    = R0 + (long)N0*192;  // 16384*128
    float* H1b   = R1 + (long)N0*128;  // 4096*128
    float* THb   = H1b + (long)N1*128; // 4096*128
    float* OUTb  = THb + (long)N1*128; // 4096*64
    float* ENC1  = OUTb + (long)N1*64; // 4096*64
    float* H2b   = ENC1 + (long)N1*64; // 1024*64
    float* HDb   = H2b + (long)N2*64;  // 1024*32
    float* HCAT  = HDb + (long)N2*32;  // 4096*96
    float* HDEC  = HCAT + (long)N1*96; // 4096*64

    // ---- head SSConv ----
    bnx_kernel<<<256, 256, 0, stream>>>(x, PART, dflag);                                    // 1
    bnfold_kernel<<<128, 256, 0, stream>>>(PART, N0, hg, hb, hpw, hpb,
                                           WF1, BF1, C_IN, 128, 1, dflag);                  // 2
    gemm4_dyn_kernel<<<(N0 * 128 / 4) / 256, 256, 0, stream>>>(x, WF1, BF1, R0, C_IN, 128, dflag); // 3
    dw4_kernel<<<(N0 * 32) / 256, 256, 0, stream>>>(R0, hdw, hdb, R1, dflag);               // 4 (R1 = enc0)
    pool4_kernel<<<(N1 * 32) / 256, 256, 0, stream>>>(R1, H1b, 128);                        // 5

    // ---- GCN e0: 128 -> 64 ----
    bnA_kernel<<<256, 256, 0, stream>>>(H1b, N1, 128, PART);                                // 6
    bnfold2_kernel<<<192, 256, 0, stream>>>(PART, N1, e0_g, e0_b, e0_wt, e0_bt, e0_wo, e0_bo,
                                            WF1, BF1, WF2, BF2, 128, 128, 64, dflag);       // 7
    {
        int nb1 = (N1 * 32) / 256, nb2 = (N1 * 16) / 256;
        gemm2_f32_kernel<0><<<nb1 + nb2, 256, 0, stream>>>(H1b, WF1, BF1, THb, 128,
                                                           WF2, BF2, OUTb, 64, 128, nb1);   // 8
    }
    attn_kernel<<<N1 / 4, 256, 0, stream>>>(THb, OUTb, nbr_a, ENC1, 64);                    // 9
    pool4_kernel<<<(N2 * 16) / 256, 256, 0, stream>>>(ENC1, H2b, 64);                       // 10

    // ---- GCN e1: 64 -> 32 ----
    bnA_kernel<<<256, 256, 0, stream>>>(H2b, N2, 64, PART);                                 // 11
    bnfold2_kernel<<<160, 256, 0, stream>>>(PART, N2, e1_g, e1_b, e1_wt, e1_bt, e1_wo, e1_bo,
                                            WF1, BF1, WF2, BF2, 64, 128, 32, dflag);        // 12
    {
        int nb1 = (N2 * 32) / 256, nb2 = (N2 * 8) / 256;
        gemm2_f32_kernel<0><<<nb1 + nb2, 256, 0, stream>>>(H2b, WF1, BF1, THb, 128,
                                                           WF2, BF2, OUTb, 32, 64, nb1);    // 13
    }
    attn_kernel<<<N2 / 4, 256, 0, stream>>>(THb, OUTb, nbr_b, HDb, 32);                     // 14

    // ---- decoder GCN d0 ----
    concat_hcat_kernel<<<(N1 * 24) / 256, 256, 0, stream>>>(HDb, ENC1, HCAT);               // 15
    bnA_kernel<<<256, 256, 0, stream>>>(HCAT, N1, 96, PART);                                // 16
    bnfold2_kernel<<<192, 256, 0, stream>>>(PART, N1, d0_g, d0_b, d0_wt, d0_bt, d0_wo, d0_bo,
                                            WF1, BF1, WF2, BF2, 96, 128, 64, dflag);        // 17
    {
        int nb1 = (N1 * 32) / 256, nb2 = (N1 * 16) / 256;
        gemm2_f32_kernel<0><<<nb1 + nb2, 256, 0, stream>>>(HCAT, WF1, BF1, THb, 128,
                                                           WF2, BF2, OUTb, 64, 96, nb1);    // 18
    }
    attn_kernel<<<N1 / 4, 256, 0, stream>>>(THb, OUTb, nbr_a, HDEC, 64);                    // 19

    // ---- tail ----
    concat_g_kernel<<<(N0 * 48) / 256, 256, 0, stream>>>(HDEC, R1, R0);                     // 20 (R0 = G)
    bnA_kernel<<<256, 256, 0, stream>>>(R0, N0, 192, PART);                                 // 21
    bnfold_kernel<<<128, 256, 0, stream>>>(PART, N0, tg, tb, tpw, tpb,
                                           WF1, BF1, 192, 128, 1, dflag);                   // 22
    gemm4_f32_kernel<1><<<(N0 * 128 / 4) / 256, 256, 0, stream>>>(R0, WF1, BF1, R1, 192, 128); // 23 (R1 = T1)
    dw4_kernel<<<(N0 * 32) / 256, 256, 0, stream>>>(R1, tdw, tdb, R0, dflag);               // 24 (R0 = F)
    cls_kernel<<<(N0 * NCLS) / 256, 256, 0, stream>>>(R0, wsw, wb, d_out, dflag);           // 25
}